// Round 6
// baseline (555.365 us; speedup 1.0000x reference)
//
#include <hip/hip_runtime.h>

#define DEV __device__ __forceinline__

using f32x4  = __attribute__((ext_vector_type(4))) float;
using bf16x8 = __attribute__((ext_vector_type(8))) __bf16;
using bf16x4 = __attribute__((ext_vector_type(4))) __bf16;

constexpr int Bc = 8, Tc = 2048, Ec = 1024, Hc = 1024;
constexpr int Mc = Bc * Tc;  // 16384 total rows

DEV f32x4 mfma16(bf16x8 a, bf16x8 b, f32x4 c) {
    return __builtin_amdgcn_mfma_f32_16x16x32_bf16(a, b, c, 0, 0, 0);
}
DEV unsigned short f16bits(float f) { return __builtin_bit_cast(unsigned short, (_Float16)f); }
DEV float f16val(unsigned short u) { return (float)__builtin_bit_cast(_Float16, u); }
DEV unsigned short bf16bits(float f) { return __builtin_bit_cast(unsigned short, (__bf16)f); }

// async global->LDS, 16B per lane. LDS dest must be wave-uniform base; HW adds lane*16.
DEV void gload16(const __bf16* g, __bf16* l) {
    __builtin_amdgcn_global_load_lds(
        (const __attribute__((address_space(1))) unsigned int*)g,
        (__attribute__((address_space(3))) unsigned int*)l, 16, 0, 0);
}

// Paired-row swizzled LDS slice layout (per 256x32 bf16 slice = 16KB):
// LDS row r (128B) holds tile-rows {2r, 2r+1}; the 8 16B slots within row r
// are XOR-permuted by (r&7).  Verified 0 bank conflicts (round 5 counters).
DEV int swz_off(int R, int lk) {
    return ((R >> 1) << 6) + ((((((R & 1) << 2) | lk) ^ ((R >> 1) & 7))) << 3);
}

// ---------------------------------------------------------------------------
// prep_x: split f32 x into hi/lo bf16 (x = hi + lo to ~17 mantissa bits)
// ---------------------------------------------------------------------------
__global__ __launch_bounds__(256) void prep_x(const float* __restrict__ x,
                                              __bf16* __restrict__ xh,
                                              __bf16* __restrict__ xl, int n) {
    int i = (blockIdx.x * 256 + threadIdx.x) * 4;
    if (i >= n) return;
    f32x4 v = *reinterpret_cast<const f32x4*>(x + i);
    bf16x4 h, l;
#pragma unroll
    for (int j = 0; j < 4; j++) {
        __bf16 hv = (__bf16)v[j];
        h[j] = hv;
        l[j] = (__bf16)(v[j] - (float)hv);
    }
    *reinterpret_cast<bf16x4*>(xh + i) = h;
    *reinterpret_cast<bf16x4*>(xl + i) = l;
}

// ---------------------------------------------------------------------------
// prep_w: transpose W[e][n] -> WT[n][e], split hi/lo bf16.
// z=0 -> Wq into combined Wqk rows [0,1024); z=1 -> Wk into rows [1024,2048);
// z=2 -> Wv (hi only).
// ---------------------------------------------------------------------------
__global__ __launch_bounds__(256) void prep_w(const float* __restrict__ wq,
                                              const float* __restrict__ wk,
                                              const float* __restrict__ wv,
                                              __bf16* __restrict__ qkh, __bf16* __restrict__ qkl,
                                              __bf16* __restrict__ vh) {
    __shared__ float tile[32][33];
    const int z = blockIdx.z;
    const float* src = (z == 0) ? wq : (z == 1) ? wk : wv;
    __bf16* dh = (z == 2) ? vh : qkh + (size_t)z * 1024 * Ec;
    __bf16* dl = (z == 2) ? nullptr : qkl + (size_t)z * 1024 * Ec;
    const int n0 = blockIdx.x * 32, e0 = blockIdx.y * 32;
    const int tx = threadIdx.x & 31, ty = threadIdx.x >> 5;  // 32 x 8
#pragma unroll
    for (int j = 0; j < 32; j += 8)
        tile[ty + j][tx] = src[(size_t)(e0 + ty + j) * Hc + n0 + tx];
    __syncthreads();
#pragma unroll
    for (int j = 0; j < 32; j += 8) {
        float v = tile[tx][ty + j];
        __bf16 h = (__bf16)v;
        size_t idx = (size_t)(n0 + ty + j) * Ec + e0 + tx;
        dh[idx] = h;
        if (dl) dl[idx] = (__bf16)(v - (float)h);
    }
}

// ---------------------------------------------------------------------------
// gemm8: 256x256 tile, 8 waves (2x4, each 128x64), 512 threads, BK-slot = 32,
// 4-slot LDS ring.  m201-style schedule: per slot, TWO phases of
// {ds_read; stage 2 gloads; barrier; setprio(1); 16 MFMA; setprio(0); barrier},
// with ONE counted vmcnt(8) gate per slot (before the slot's exit barrier).
// Steady state keeps 12 loads in flight; gate exposes zero latency.
// Cross-wave safety: each wave's gate precedes the shared exit barrier, so
// slot P+1's collective staging is complete for all waves after it.
// NTERMS==3: virtual K = 3*1024, per-slice remap (AhBh + AlBh + AhBl).
// EPI: 0 = bf16 hi/lo out, N=2048 split into Q (gn<1024) / K (gn>=1024)
//      1 = bf16 transposed store Vt[b][n][t] (V proj)
//      2 = f16 causal energy * 1/sqrt(dk), tile-skip bx>by
//      3 = f32 row-major (PV), nkt = (by+1)*8
// ---------------------------------------------------------------------------
template <int NTERMS, int EPI>
__global__ __launch_bounds__(512, 2) void gemm8(
        const __bf16* __restrict__ Ah, const __bf16* __restrict__ Al,
        const __bf16* __restrict__ Bh, const __bf16* __restrict__ Bl,
        void* __restrict__ out0, void* __restrict__ out1,
        void* __restrict__ out2, void* __restrict__ out3,
        const int* __restrict__ dkp,
        int lda, int ldb, size_t aBS, size_t bBS, size_t oBS, int nkt) {
    __shared__ __bf16 sA[4][256 * 32];  // 64 KiB
    __shared__ __bf16 sB[4][256 * 32];  // 64 KiB

    constexpr int SWZ = (EPI == 0) ? 8 : (EPI == 1) ? 4 : 0;  // grid bx count
    int bx = blockIdx.x, by = blockIdx.y;
    if (SWZ == 8) {  // grid (8,64): XCD x owns by in [8x,8x+8)
        const int lin = by * 8 + bx;
        const int w = (lin & 7) * 64 + (lin >> 3);
        by = w >> 3; bx = w & 7;
    } else if (SWZ == 4) {  // grid (4,64)
        const int lin = by * 4 + bx;
        const int w = (lin & 7) * 32 + (lin >> 3);
        by = w >> 2; bx = w & 3;
    }
    if (EPI == 2 && bx > by) return;  // upper-triangle tiles: softmax masks them
    if (EPI == 3) nkt = (by + 1) * 8;  // causal K extent

    const int z = blockIdx.z;
    Ah += (size_t)z * aBS;
    Bh += (size_t)z * bBS;
    if (NTERMS == 3) { Al += (size_t)z * aBS; Bl += (size_t)z * bBS; }

    const float scale = (EPI == 2) ? (1.0f / sqrtf((float)*dkp)) : 1.0f;  // s_load, pre-loop

    const int tid = threadIdx.x;
    const int wave = tid >> 6, lane = tid & 63;
    const int lr = lane & 15, lk = lane >> 4;
    const int wm = wave >> 2, wn = wave & 3;  // 2 x 4 wave grid
    const int m0 = by * 256, n0 = bx * 256;

    // staging constants (inverse-swizzled global source, linear LDS dest):
    const int so = (lane & 7) ^ (lane >> 3);       // original 16B-slot index
    const int strow = 2 * (lane >> 3) + (so >> 2); // tile-row offset in 16-row grp
    const int stcol = (so & 3) * 8;                // element col offset within 32

    auto srcs = [&](int sv, const __bf16*& as, const __bf16*& bs, int& kk) {
        if (NTERMS == 3) {
            const int term = sv >> 5;
            kk = (sv & 31) * 32;
            as = (term == 1) ? Al : Ah;
            bs = (term == 2) ? Bl : Bh;
        } else {
            as = Ah; bs = Bh; kk = sv * 32;
        }
    };
    auto stageA = [&](int sv) {
        const __bf16 *as, *bs; int kk; srcs(sv, as, bs, kk);
        const int slot = sv & 3;
#pragma unroll
        for (int l = 0; l < 2; l++) {
            const int bi = wave * 2 + l;
            gload16(as + (size_t)(m0 + bi * 16 + strow) * lda + kk + stcol,
                    &sA[slot][bi * 512]);
        }
    };
    auto stageB = [&](int sv) {
        const __bf16 *as, *bs; int kk; srcs(sv, as, bs, kk);
        const int slot = sv & 3;
#pragma unroll
        for (int l = 0; l < 2; l++) {
            const int bi = wave * 2 + l;
            gload16(bs + (size_t)(n0 + bi * 16 + strow) * ldb + kk + stcol,
                    &sB[slot][bi * 512]);
        }
    };

    f32x4 acc[8][4] = {};

    // prologue: 3 slots in flight (12 loads/wave)
    stageA(0); stageB(0);
    stageA(1); stageB(1);
    stageA(2); stageB(2);
    asm volatile("s_waitcnt vmcnt(8)" ::: "memory");  // slot 0 complete
    __builtin_amdgcn_s_barrier();

    for (int P = 0; P < nkt; ++P) {
        const int slot = P & 3;
        bf16x8 af[4], bfr[4];

        // ---- even phase: A(mi 0-3) + B frags; stage A-pair of slot P+3 ----
#pragma unroll
        for (int mi = 0; mi < 4; mi++)
            af[mi] = *reinterpret_cast<const bf16x8*>(
                &sA[slot][swz_off(wm * 128 + mi * 16 + lr, lk)]);
#pragma unroll
        for (int nj = 0; nj < 4; nj++)
            bfr[nj] = *reinterpret_cast<const bf16x8*>(
                &sB[slot][swz_off(wn * 64 + nj * 16 + lr, lk)]);
        if (P + 3 < nkt) stageA(P + 3);
        __builtin_amdgcn_s_barrier();
        __builtin_amdgcn_s_setprio(1);
#pragma unroll
        for (int mi = 0; mi < 4; mi++)
#pragma unroll
            for (int nj = 0; nj < 4; nj++)
                acc[mi][nj] = mfma16(af[mi], bfr[nj], acc[mi][nj]);
        __builtin_amdgcn_s_setprio(0);
        __builtin_amdgcn_s_barrier();

        // ---- odd phase: A(mi 4-7); stage B-pair; slot gate; exit ----
#pragma unroll
        for (int mi = 0; mi < 4; mi++)
            af[mi] = *reinterpret_cast<const bf16x8*>(
                &sA[slot][swz_off(wm * 128 + (mi + 4) * 16 + lr, lk)]);
        if (P + 3 < nkt) stageB(P + 3);
        __builtin_amdgcn_s_barrier();
        __builtin_amdgcn_s_setprio(1);
#pragma unroll
        for (int mi = 0; mi < 4; mi++)
#pragma unroll
            for (int nj = 0; nj < 4; nj++)
                acc[mi + 4][nj] = mfma16(af[mi], bfr[nj], acc[mi + 4][nj]);
        __builtin_amdgcn_s_setprio(0);
        // counted slot-boundary gate: slot P+1 must be complete after this
        const int rem = nkt - 2 - P;  // slots staged after slot P+1
        if (rem >= 2)      asm volatile("s_waitcnt vmcnt(8)" ::: "memory");
        else if (rem == 1) asm volatile("s_waitcnt vmcnt(4)" ::: "memory");
        else if (rem == 0) asm volatile("s_waitcnt vmcnt(0)" ::: "memory");
        __builtin_amdgcn_s_barrier();
    }

#pragma unroll
    for (int mi = 0; mi < 8; mi++)
#pragma unroll
        for (int nj = 0; nj < 4; nj++) {
            const int gn = n0 + wn * 64 + nj * 16 + lr;
            if (EPI == 1) {
                const int gm0 = m0 + wm * 128 + mi * 16 + lk * 4;
                const int bb = gm0 >> 11, t = gm0 & (Tc - 1);
                bf16x4 pk;
#pragma unroll
                for (int r = 0; r < 4; r++) pk[r] = (__bf16)acc[mi][nj][r];
                *reinterpret_cast<bf16x4*>(
                    &((__bf16*)out0)[((size_t)(bb * Hc + gn)) * Tc + t]) = pk;
            } else if (EPI == 0) {
                __bf16* oh = (gn < 1024) ? (__bf16*)out0 : (__bf16*)out2;
                __bf16* ol = (gn < 1024) ? (__bf16*)out1 : (__bf16*)out3;
                const int cc = gn & 1023;
#pragma unroll
                for (int r = 0; r < 4; r++) {
                    const int gm = m0 + wm * 128 + mi * 16 + lk * 4 + r;
                    const float v = acc[mi][nj][r];
                    __bf16 h = (__bf16)v;
                    oh[(size_t)gm * Hc + cc] = h;
                    ol[(size_t)gm * Hc + cc] = (__bf16)(v - (float)h);
                }
            } else {
#pragma unroll
                for (int r = 0; r < 4; r++) {
                    const int gm = m0 + wm * 128 + mi * 16 + lk * 4 + r;
                    const float v = acc[mi][nj][r];
                    if (EPI == 2) {
                        const float e = (gn > gm) ? -INFINITY : v * scale;
                        ((unsigned short*)out0)[(size_t)z * oBS + (size_t)gm * Tc + gn] =
                            f16bits(e);
                    } else {
                        ((float*)out0)[(size_t)z * oBS + (size_t)gm * Hc + gn] = v;
                    }
                }
            }
        }
}

// ---------------------------------------------------------------------------
// softmax_k: one block per (b,q) row.  Reads f16 logits, writes bf16 P in
// place.  k>q forced to -inf (covers never-written upper tiles); P[k>q]=0.
// ---------------------------------------------------------------------------
__global__ __launch_bounds__(256) void softmax_k(unsigned short* __restrict__ S) {
    const int q = blockIdx.x & (Tc - 1);
    const int b = blockIdx.x >> 11;
    const int tid = threadIdx.x;
    const int c0 = tid * 8;
    unsigned short* row = S + ((size_t)b * Tc + q) * Tc;

    uint4 raw = *reinterpret_cast<const uint4*>(row + c0);
    unsigned u[4] = {raw.x, raw.y, raw.z, raw.w};
    float v[8];
#pragma unroll
    for (int p = 0; p < 4; p++) {
        v[2 * p]     = f16val((unsigned short)(u[p] & 0xFFFFu));
        v[2 * p + 1] = f16val((unsigned short)(u[p] >> 16));
    }
#pragma unroll
    for (int i = 0; i < 8; i++)
        if (c0 + i > q) v[i] = -INFINITY;

    float m = v[0];
#pragma unroll
    for (int i = 1; i < 8; i++) m = fmaxf(m, v[i]);
#pragma unroll
    for (int off = 1; off < 64; off <<= 1) m = fmaxf(m, __shfl_xor(m, off));
    __shared__ float red[4];
    if ((tid & 63) == 0) red[tid >> 6] = m;
    __syncthreads();
    m = fmaxf(fmaxf(red[0], red[1]), fmaxf(red[2], red[3]));

    float e[8], s = 0.f;
#pragma unroll
    for (int i = 0; i < 8; i++) {
        e[i] = __expf(v[i] - m);  // exp(-inf)=0
        s += e[i];
    }
#pragma unroll
    for (int off = 1; off < 64; off <<= 1) s += __shfl_xor(s, off);
    __syncthreads();
    if ((tid & 63) == 0) red[tid >> 6] = s;
    __syncthreads();
    s = red[0] + red[1] + red[2] + red[3];
    const float inv = 1.0f / s;

    unsigned o[4];
#pragma unroll
    for (int p = 0; p < 4; p++) {
        unsigned short a = bf16bits(e[2 * p] * inv);
        unsigned short bb = bf16bits(e[2 * p + 1] * inv);
        o[p] = (unsigned)a | ((unsigned)bb << 16);
    }
    uint4 w; w.x = o[0]; w.y = o[1]; w.z = o[2]; w.w = o[3];
    *reinterpret_cast<uint4*>(row + c0) = w;
}

// ---------------------------------------------------------------------------
extern "C" void kernel_launch(void* const* d_in, const int* in_sizes, int n_in,
                              void* d_out, int out_size, void* d_ws, size_t ws_size,
                              hipStream_t stream) {
    const float* x  = (const float*)d_in[0];
    const float* Wq = (const float*)d_in[1];
    const float* Wk = (const float*)d_in[2];
    const float* Wv = (const float*)d_in[3];
    const int*   dk = (const int*)d_in[4];
    float* out = (float*)d_out;
    char* ws = (char*)d_ws;

    const size_t SZ_XE = (size_t)Mc * Ec * 2;  // 32 MiB
    const size_t SZ_W  = (size_t)Ec * Hc * 2;  // 2 MiB

    size_t o = 0;
    auto nxt = [&](size_t bytes) { void* p = ws + o; o += bytes; return p; };
    __bf16* Xh    = (__bf16*)nxt(SZ_XE);
    __bf16* Xl    = (__bf16*)nxt(SZ_XE);
    __bf16* WqkhT = (__bf16*)nxt(2 * SZ_W);  // [2048][1024] combined Wq|Wk hi
    __bf16* WqklT = (__bf16*)nxt(2 * SZ_W);  // combined lo
    __bf16* WvhT  = (__bf16*)nxt(SZ_W);
    __bf16* Qh    = (__bf16*)nxt(SZ_XE);
    __bf16* Ql    = (__bf16*)nxt(SZ_XE);
    __bf16* Kh    = (__bf16*)nxt(SZ_XE);
    __bf16* Kl    = (__bf16*)nxt(SZ_XE);
    __bf16* Vt    = (__bf16*)nxt(SZ_XE);
    // S: all-batch f16 [8][2048][2048] = 64 MiB, aliases Xh+Xl (dead after projections)
    unsigned short* S = (unsigned short*)Xh;
    (void)ws_size; (void)in_sizes; (void)n_in; (void)out_size;

    prep_x<<<(Mc * Ec / 4 + 255) / 256, 256, 0, stream>>>(x, Xh, Xl, Mc * Ec);
    prep_w<<<dim3(32, 32, 3), 256, 0, stream>>>(Wq, Wk, Wv, WqkhT, WqklT, WvhT);

    // merged Q+K projection: N=2048 over [Wq|Wk], virtual K=3072, hi/lo out
    gemm8<3, 0><<<dim3(8, 64), 512, 0, stream>>>(
        Xh, Xl, WqkhT, WqklT, Qh, Ql, Kh, Kl, dk, Ec, Ec, 0, 0, 0, 96);
    // V projection: 1-term, transposed store Vt[b][dout][t]
    gemm8<1, 1><<<dim3(4, 64), 512, 0, stream>>>(
        Xh, nullptr, WvhT, nullptr, Vt, nullptr, nullptr, nullptr, dk,
        Ec, Ec, 0, 0, 0, 32);

    // energy: all batches, causal tiles only, f16 logits, virtual K=3072
    gemm8<3, 2><<<dim3(8, 8, Bc), 512, 0, stream>>>(
        Qh, Ql, Kh, Kl, S, nullptr, nullptr, nullptr, dk, Hc, Hc,
        (size_t)Tc * Hc, (size_t)Tc * Hc, (size_t)Tc * Tc, 96);

    softmax_k<<<Bc * Tc, 256, 0, stream>>>(S);

    // PV: all batches, nkt=(by+1)*8 (P beyond causal edge is 0)
    gemm8<1, 3><<<dim3(4, 8, Bc), 512, 0, stream>>>(
        (const __bf16*)S, nullptr, Vt, nullptr, out, nullptr, nullptr, nullptr, dk,
        Tc, Tc, (size_t)Tc * Tc, (size_t)Hc * Tc, (size_t)Tc * Hc, 0);
}

// Round 7
// 433.906 us; speedup vs baseline: 1.2799x; 1.2799x over previous
//
#include <hip/hip_runtime.h>

#define DEV __device__ __forceinline__

using f32x4  = __attribute__((ext_vector_type(4))) float;
using bf16x8 = __attribute__((ext_vector_type(8))) __bf16;
using bf16x4 = __attribute__((ext_vector_type(4))) __bf16;

constexpr int Bc = 8, Tc = 2048, Ec = 1024, Hc = 1024;
constexpr int Mc = Bc * Tc;  // 16384 total rows

DEV f32x4 mfma16(bf16x8 a, bf16x8 b, f32x4 c) {
    return __builtin_amdgcn_mfma_f32_16x16x32_bf16(a, b, c, 0, 0, 0);
}
DEV unsigned short f16bits(float f) { return __builtin_bit_cast(unsigned short, (_Float16)f); }
DEV float f16val(unsigned short u) { return (float)__builtin_bit_cast(_Float16, u); }
DEV unsigned short bf16bits(float f) { return __builtin_bit_cast(unsigned short, (__bf16)f); }

// async global->LDS, 16B per lane. LDS dest must be wave-uniform base; HW adds lane*16.
DEV void gload16(const __bf16* g, __bf16* l) {
    __builtin_amdgcn_global_load_lds(
        (const __attribute__((address_space(1))) unsigned int*)g,
        (__attribute__((address_space(3))) unsigned int*)l, 16, 0, 0);
}

// Paired-row swizzled LDS slice layout (per 256x32 bf16 slice = 16KB):
// LDS row r (128B) holds tile-rows {2r, 2r+1}; the 8 16B slots within row r
// are XOR-permuted by (r&7).  Verified 0 bank conflicts (round 5/6 counters).
DEV int swz_off(int R, int lk) {
    return ((R >> 1) << 6) + ((((((R & 1) << 2) | lk) ^ ((R >> 1) & 7))) << 3);
}

// ---------------------------------------------------------------------------
// prep_x: split f32 x into hi/lo bf16 (x = hi + lo to ~17 mantissa bits)
// ---------------------------------------------------------------------------
__global__ __launch_bounds__(256) void prep_x(const float* __restrict__ x,
                                              __bf16* __restrict__ xh,
                                              __bf16* __restrict__ xl, int n) {
    int i = (blockIdx.x * 256 + threadIdx.x) * 4;
    if (i >= n) return;
    f32x4 v = *reinterpret_cast<const f32x4*>(x + i);
    bf16x4 h, l;
#pragma unroll
    for (int j = 0; j < 4; j++) {
        __bf16 hv = (__bf16)v[j];
        h[j] = hv;
        l[j] = (__bf16)(v[j] - (float)hv);
    }
    *reinterpret_cast<bf16x4*>(xh + i) = h;
    *reinterpret_cast<bf16x4*>(xl + i) = l;
}

// ---------------------------------------------------------------------------
// prep_w: transpose W[e][n] -> WT[n][e], bf16 hi only (2-term split keeps the
// lo residual on the A side; B-side lo dropped — error analysis in notes).
// Combined dest Wall[3072][1024]: rows [0,1024)=Wq, [1024,2048)=Wk, [2048,3072)=Wv.
// ---------------------------------------------------------------------------
__global__ __launch_bounds__(256) void prep_w(const float* __restrict__ wq,
                                              const float* __restrict__ wk,
                                              const float* __restrict__ wv,
                                              __bf16* __restrict__ wall) {
    __shared__ float tile[32][33];
    const int z = blockIdx.z;
    const float* src = (z == 0) ? wq : (z == 1) ? wk : wv;
    __bf16* dh = wall + (size_t)z * 1024 * Ec;
    const int n0 = blockIdx.x * 32, e0 = blockIdx.y * 32;
    const int tx = threadIdx.x & 31, ty = threadIdx.x >> 5;  // 32 x 8
#pragma unroll
    for (int j = 0; j < 32; j += 8)
        tile[ty + j][tx] = src[(size_t)(e0 + ty + j) * Hc + n0 + tx];
    __syncthreads();
#pragma unroll
    for (int j = 0; j < 32; j += 8)
        dh[(size_t)(n0 + ty + j) * Ec + e0 + tx] = (__bf16)tile[tx][ty + j];
}

// ---------------------------------------------------------------------------
// gemm8: 256x256 tile, 8 waves (2x4, each 128x64), 512 threads, BK-slot = 32,
// 4-slot LDS ring.  Schedule (round-6, measured MfmaUtil 40%, conflicts 0):
// per slot TWO phases of {ds_read; stage 2 gloads; barrier; setprio(1);
// 16 MFMA; setprio(0); barrier}, ONE counted vmcnt gate per slot.
// NTERMS==2: virtual K = 2*1024, slice term 0: Ah*Bh, term 1: Al*Bh
//            (2-term split: B-side lo dropped, A-side lo kept).
// EPI: 0 = bf16 out, N=2048 split: Q (gn<1024) hi/lo, K (gn>=1024) hi only
//      1 = bf16 transposed store Vt[b][n][t] (V proj)
//      2 = f16 causal energy * 1/sqrt(dk), tile-skip bx>by
//      3 = f32 row-major (PV), nkt = (by+1)*8
// ---------------------------------------------------------------------------
template <int NTERMS, int EPI>
__global__ __launch_bounds__(512, 2) void gemm8(
        const __bf16* __restrict__ Ah, const __bf16* __restrict__ Al,
        const __bf16* __restrict__ Bh,
        void* __restrict__ out0, void* __restrict__ out1,
        void* __restrict__ out2, void* __restrict__ out3,
        const int* __restrict__ dkp,
        int lda, int ldb, size_t aBS, size_t bBS, size_t oBS, int nkt) {
    __shared__ __bf16 sA[4][256 * 32];  // 64 KiB
    __shared__ __bf16 sB[4][256 * 32];  // 64 KiB

    constexpr int SWZ = (EPI == 0) ? 8 : (EPI == 1) ? 4 : 0;  // grid bx count
    int bx = blockIdx.x, by = blockIdx.y;
    if (SWZ == 8) {  // grid (8,64): bijective XCD chunking
        const int lin = by * 8 + bx;
        const int w = (lin & 7) * 64 + (lin >> 3);
        by = w >> 3; bx = w & 7;
    } else if (SWZ == 4) {  // grid (4,64)
        const int lin = by * 4 + bx;
        const int w = (lin & 7) * 32 + (lin >> 3);
        by = w >> 2; bx = w & 3;
    }
    if (EPI == 2 && bx > by) return;  // upper-triangle tiles: softmax masks them
    if (EPI == 3) nkt = (by + 1) * 8;  // causal K extent

    const int z = blockIdx.z;
    Ah += (size_t)z * aBS;
    Bh += (size_t)z * bBS;
    if (NTERMS == 2) Al += (size_t)z * aBS;

    const float scale = (EPI == 2) ? (1.0f / sqrtf((float)*dkp)) : 1.0f;

    const int tid = threadIdx.x;
    const int wave = tid >> 6, lane = tid & 63;
    const int lr = lane & 15, lk = lane >> 4;
    const int wm = wave >> 2, wn = wave & 3;  // 2 x 4 wave grid
    const int m0 = by * 256, n0 = bx * 256;

    // staging constants (inverse-swizzled global source, linear LDS dest):
    const int so = (lane & 7) ^ (lane >> 3);       // original 16B-slot index
    const int strow = 2 * (lane >> 3) + (so >> 2); // tile-row offset in 16-row grp
    const int stcol = (so & 3) * 8;                // element col offset within 32

    auto srcs = [&](int sv, const __bf16*& as, int& kk) {
        if (NTERMS == 2) {
            as = (sv >> 5) ? Al : Ah;
            kk = (sv & 31) * 32;
        } else {
            as = Ah; kk = sv * 32;
        }
    };
    auto stageA = [&](int sv) {
        const __bf16* as; int kk; srcs(sv, as, kk);
        const int slot = sv & 3;
#pragma unroll
        for (int l = 0; l < 2; l++) {
            const int bi = wave * 2 + l;
            gload16(as + (size_t)(m0 + bi * 16 + strow) * lda + kk + stcol,
                    &sA[slot][bi * 512]);
        }
    };
    auto stageB = [&](int sv) {
        const __bf16* as; int kk; srcs(sv, as, kk);
        const int slot = sv & 3;
#pragma unroll
        for (int l = 0; l < 2; l++) {
            const int bi = wave * 2 + l;
            gload16(Bh + (size_t)(n0 + bi * 16 + strow) * ldb + kk + stcol,
                    &sB[slot][bi * 512]);
        }
    };

    f32x4 acc[8][4] = {};

    // prologue: 3 slots in flight (12 loads/wave)
    stageA(0); stageB(0);
    stageA(1); stageB(1);
    stageA(2); stageB(2);
    asm volatile("s_waitcnt vmcnt(8)" ::: "memory");  // slot 0 complete
    __builtin_amdgcn_s_barrier();

    for (int P = 0; P < nkt; ++P) {
        const int slot = P & 3;
        bf16x8 af[4], bfr[4];

        // ---- even phase: A(mi 0-3) + B frags; stage A-pair of slot P+3 ----
#pragma unroll
        for (int mi = 0; mi < 4; mi++)
            af[mi] = *reinterpret_cast<const bf16x8*>(
                &sA[slot][swz_off(wm * 128 + mi * 16 + lr, lk)]);
#pragma unroll
        for (int nj = 0; nj < 4; nj++)
            bfr[nj] = *reinterpret_cast<const bf16x8*>(
                &sB[slot][swz_off(wn * 64 + nj * 16 + lr, lk)]);
        if (P + 3 < nkt) stageA(P + 3);
        __builtin_amdgcn_s_barrier();
        __builtin_amdgcn_s_setprio(1);
#pragma unroll
        for (int mi = 0; mi < 4; mi++)
#pragma unroll
            for (int nj = 0; nj < 4; nj++)
                acc[mi][nj] = mfma16(af[mi], bfr[nj], acc[mi][nj]);
        __builtin_amdgcn_s_setprio(0);
        __builtin_amdgcn_s_barrier();

        // ---- odd phase: A(mi 4-7); stage B-pair; slot gate; exit ----
#pragma unroll
        for (int mi = 0; mi < 4; mi++)
            af[mi] = *reinterpret_cast<const bf16x8*>(
                &sA[slot][swz_off(wm * 128 + (mi + 4) * 16 + lr, lk)]);
        if (P + 3 < nkt) stageB(P + 3);
        __builtin_amdgcn_s_barrier();
        __builtin_amdgcn_s_setprio(1);
#pragma unroll
        for (int mi = 0; mi < 4; mi++)
#pragma unroll
            for (int nj = 0; nj < 4; nj++)
                acc[mi + 4][nj] = mfma16(af[mi], bfr[nj], acc[mi + 4][nj]);
        __builtin_amdgcn_s_setprio(0);
        // counted slot-boundary gate: slot P+1 must be complete after this
        const int rem = nkt - 2 - P;  // slots staged beyond slot P+1
        if (rem >= 2)      asm volatile("s_waitcnt vmcnt(8)" ::: "memory");
        else if (rem == 1) asm volatile("s_waitcnt vmcnt(4)" ::: "memory");
        else if (rem == 0) asm volatile("s_waitcnt vmcnt(0)" ::: "memory");
        __builtin_amdgcn_s_barrier();
    }

#pragma unroll
    for (int mi = 0; mi < 8; mi++)
#pragma unroll
        for (int nj = 0; nj < 4; nj++) {
            const int gn = n0 + wn * 64 + nj * 16 + lr;
            if (EPI == 1) {
                const int gm0 = m0 + wm * 128 + mi * 16 + lk * 4;
                const int bb = gm0 >> 11, t = gm0 & (Tc - 1);
                bf16x4 pk;
#pragma unroll
                for (int r = 0; r < 4; r++) pk[r] = (__bf16)acc[mi][nj][r];
                *reinterpret_cast<bf16x4*>(
                    &((__bf16*)out0)[((size_t)(bb * Hc + gn)) * Tc + t]) = pk;
            } else if (EPI == 0) {
                __bf16* oh = (gn < 1024) ? (__bf16*)out0 : (__bf16*)out2;
                __bf16* ol = (gn < 1024) ? (__bf16*)out1 : (__bf16*)out3;
                const int cc = gn & 1023;
#pragma unroll
                for (int r = 0; r < 4; r++) {
                    const int gm = m0 + wm * 128 + mi * 16 + lk * 4 + r;
                    const float v = acc[mi][nj][r];
                    __bf16 h = (__bf16)v;
                    oh[(size_t)gm * Hc + cc] = h;
                    if (ol) ol[(size_t)gm * Hc + cc] = (__bf16)(v - (float)h);
                }
            } else {
#pragma unroll
                for (int r = 0; r < 4; r++) {
                    const int gm = m0 + wm * 128 + mi * 16 + lk * 4 + r;
                    const float v = acc[mi][nj][r];
                    if (EPI == 2) {
                        const float e = (gn > gm) ? -INFINITY : v * scale;
                        ((unsigned short*)out0)[(size_t)z * oBS + (size_t)gm * Tc + gn] =
                            f16bits(e);
                    } else {
                        ((float*)out0)[(size_t)z * oBS + (size_t)gm * Hc + gn] = v;
                    }
                }
            }
        }
}

// ---------------------------------------------------------------------------
// softmax_k: one block per (b,q) row.  Reads f16 logits, writes bf16 P in
// place.  k>q forced to -inf (covers never-written upper tiles); P[k>q]=0.
// ---------------------------------------------------------------------------
__global__ __launch_bounds__(256) void softmax_k(unsigned short* __restrict__ S) {
    const int q = blockIdx.x & (Tc - 1);
    const int b = blockIdx.x >> 11;
    const int tid = threadIdx.x;
    const int c0 = tid * 8;
    unsigned short* row = S + ((size_t)b * Tc + q) * Tc;

    uint4 raw = *reinterpret_cast<const uint4*>(row + c0);
    unsigned u[4] = {raw.x, raw.y, raw.z, raw.w};
    float v[8];
#pragma unroll
    for (int p = 0; p < 4; p++) {
        v[2 * p]     = f16val((unsigned short)(u[p] & 0xFFFFu));
        v[2 * p + 1] = f16val((unsigned short)(u[p] >> 16));
    }
#pragma unroll
    for (int i = 0; i < 8; i++)
        if (c0 + i > q) v[i] = -INFINITY;

    float m = v[0];
#pragma unroll
    for (int i = 1; i < 8; i++) m = fmaxf(m, v[i]);
#pragma unroll
    for (int off = 1; off < 64; off <<= 1) m = fmaxf(m, __shfl_xor(m, off));
    __shared__ float red[4];
    if ((tid & 63) == 0) red[tid >> 6] = m;
    __syncthreads();
    m = fmaxf(fmaxf(red[0], red[1]), fmaxf(red[2], red[3]));

    float e[8], s = 0.f;
#pragma unroll
    for (int i = 0; i < 8; i++) {
        e[i] = __expf(v[i] - m);  // exp(-inf)=0
        s += e[i];
    }
#pragma unroll
    for (int off = 1; off < 64; off <<= 1) s += __shfl_xor(s, off);
    __syncthreads();
    if ((tid & 63) == 0) red[tid >> 6] = s;
    __syncthreads();
    s = red[0] + red[1] + red[2] + red[3];
    const float inv = 1.0f / s;

    unsigned o[4];
#pragma unroll
    for (int p = 0; p < 4; p++) {
        unsigned short a = bf16bits(e[2 * p] * inv);
        unsigned short bb = bf16bits(e[2 * p + 1] * inv);
        o[p] = (unsigned)a | ((unsigned)bb << 16);
    }
    uint4 w; w.x = o[0]; w.y = o[1]; w.z = o[2]; w.w = o[3];
    *reinterpret_cast<uint4*>(row + c0) = w;
}

// ---------------------------------------------------------------------------
extern "C" void kernel_launch(void* const* d_in, const int* in_sizes, int n_in,
                              void* d_out, int out_size, void* d_ws, size_t ws_size,
                              hipStream_t stream) {
    const float* x  = (const float*)d_in[0];
    const float* Wq = (const float*)d_in[1];
    const float* Wk = (const float*)d_in[2];
    const float* Wv = (const float*)d_in[3];
    const int*   dk = (const int*)d_in[4];
    float* out = (float*)d_out;
    char* ws = (char*)d_ws;

    const size_t SZ_XE = (size_t)Mc * Ec * 2;  // 32 MiB
    const size_t SZ_W  = (size_t)Ec * Hc * 2;  // 2 MiB

    size_t o = 0;
    auto nxt = [&](size_t bytes) { void* p = ws + o; o += bytes; return p; };
    __bf16* Xh   = (__bf16*)nxt(SZ_XE);
    __bf16* Xl   = (__bf16*)nxt(SZ_XE);
    __bf16* Wall = (__bf16*)nxt(3 * SZ_W);  // [3072][1024] = Wq|Wk|Wv hi, transposed
    __bf16* Qh   = (__bf16*)nxt(SZ_XE);
    __bf16* Ql   = (__bf16*)nxt(SZ_XE);
    __bf16* Kh   = (__bf16*)nxt(SZ_XE);
    __bf16* Vt   = (__bf16*)nxt(SZ_XE);
    // S: all-batch f16 [8][2048][2048] = 64 MiB, aliases Xh+Xl (dead after projections)
    unsigned short* S = (unsigned short*)Xh;
    (void)ws_size; (void)in_sizes; (void)n_in; (void)out_size;

    prep_x<<<(Mc * Ec / 4 + 255) / 256, 256, 0, stream>>>(x, Xh, Xl, Mc * Ec);
    prep_w<<<dim3(32, 32, 3), 256, 0, stream>>>(Wq, Wk, Wv, Wall);

    // merged Q+K projection: N=2048 over [Wq|Wk] hi, virtual K=2048
    // (2-term: XhW + XlW); Q out hi/lo, K out hi only.
    gemm8<2, 0><<<dim3(8, 64), 512, 0, stream>>>(
        Xh, Xl, Wall, Qh, Ql, Kh, nullptr, dk, Ec, Ec, 0, 0, 0, 64);
    // V projection: 1-term (Xh only), transposed store Vt[b][dout][t]
    gemm8<1, 1><<<dim3(4, 64), 512, 0, stream>>>(
        Xh, nullptr, Wall + (size_t)2048 * Ec, Vt, nullptr, nullptr, nullptr, dk,
        Ec, Ec, 0, 0, 0, 32);

    // energy: all batches, causal tiles only, f16 logits, virtual K=2048
    // (2-term: QhKh + QlKh = Q(17bit)·Kh)
    gemm8<2, 2><<<dim3(8, 8, Bc), 512, 0, stream>>>(
        Qh, Ql, Kh, S, nullptr, nullptr, nullptr, dk, Hc, Hc,
        (size_t)Tc * Hc, (size_t)Tc * Hc, (size_t)Tc * Tc, 64);

    softmax_k<<<Bc * Tc, 256, 0, stream>>>(S);

    // PV: all batches, nkt=(by+1)*8 (P beyond causal edge is 0)
    gemm8<1, 3><<<dim3(4, 8, Bc), 512, 0, stream>>>(
        (const __bf16*)S, nullptr, Vt, out, nullptr, nullptr, nullptr, dk,
        Tc, Tc, (size_t)Tc * Tc, (size_t)Hc * Tc, (size_t)Tc * Hc, 0);
}